// Round 7
// baseline (129.484 us; speedup 1.0000x reference)
//
#include <hip/hip_runtime.h>

#define T_STEPS 50000
#define HID     512
#define LBASE   128
#define CHUNKS  ((T_STEPS + LBASE - 1) / LBASE)   // 391 (last chunk = 80 steps)
#define WARMCH  3                                  // s1 warmup = 384 steps
#define NPAD    (T_STEPS + 64)                     // prefetch overshoot pad

// ---------------------------------------------------------------------------
// Kernel 1: pack per-step uniform scalars {prcp, temp, pet} as float4.
// ---------------------------------------------------------------------------
__global__ void pet_pack_kernel(const float* __restrict__ x,
                                float4* __restrict__ ptp) {
    int i = blockIdx.x * 256 + threadIdx.x;
    if (i >= NPAD) return;
    float4 v = make_float4(0.f, 0.f, 0.f, 0.f);
    if (i < T_STEPS) {
        float p  = x[3 * i + 0];
        float tt = x[3 * i + 1];
        float ld = x[3 * i + 2];
        float esat = 0.611f * __expf(17.3f * tt / (tt + 237.3f));
        float pe   = 29.8f * (ld * 24.0f) * esat / (tt + 273.2f);
        v = make_float4(p, tt, pe, 0.f);
    }
    ptp[i] = v;
}

// ---------------------------------------------------------------------------
// Snow bucket is max-plus linear (Lindley):  s0' = max(s0 + d, ps),
// d = ps - cap, cap = max(df*(t-tmax), 0).  Segment summary (D, M) composes
// as x -> max(x + D, M).   Pass A: per-(chunk,unit) aggregates in double.
// ---------------------------------------------------------------------------
__global__ __launch_bounds__(64)
void lindley_agg_kernel(const float4* __restrict__ ptp,
                        const float* __restrict__ df_,
                        const float* __restrict__ tmax_,
                        const float* __restrict__ tmin_,
                        double2* __restrict__ dm) {
    const int b     = blockIdx.x;          // 0..CHUNKS*8-1
    const int chunk = b >> 3;
    const int h     = ((b & 7) << 6) | (int)threadIdx.x;

    const float DF = df_[h], TMX = tmax_[h], TMN = tmin_[h];
    const float ndftmx = -(DF * TMX);

    const int cL  = chunk * LBASE;
    const int cE  = (cL + LBASE < T_STEPS) ? (cL + LBASE) : T_STEPS;
    const int n16 = (cE - cL) >> 4;        // 8, or 5 for the tail chunk

    const float4* vp = ptp + cL;
    asm volatile("" : "+v"(vp));           // keep loads vector (in-order vmcnt)

    float4 bufA[8], bufB[8];
#pragma unroll
    for (int i = 0; i < 8; ++i) bufA[i] = vp[i];
#pragma unroll
    for (int i = 0; i < 8; ++i) bufB[i] = vp[8 + i];

    double D = 0.0, M = -1.0e300;
#define AGG(P, TT)                                                            \
    {                                                                         \
        const float cap = fmaxf(fmaf(DF, (TT), ndftmx), 0.0f);                \
        const float ps  = ((TT) <= TMN) ? (P) : 0.0f;                         \
        const double d  = (double)ps - (double)cap;                           \
        D += d;                                                               \
        M = fmax(M + d, (double)ps);                                          \
    }
    for (int it = 0; it < n16; ++it) {
#pragma unroll
        for (int i = 0; i < 8; ++i) AGG(bufA[i].x, bufA[i].y);
#pragma unroll
        for (int i = 0; i < 8; ++i) bufA[i] = vp[16 + i];
#pragma unroll
        for (int i = 0; i < 8; ++i) AGG(bufB[i].x, bufB[i].y);
#pragma unroll
        for (int i = 0; i < 8; ++i) bufB[i] = vp[24 + i];
        vp += 16;
    }
#undef AGG
    dm[chunk * HID + h] = make_double2(D, M);
}

// ---------------------------------------------------------------------------
// Pass B: compose the CHUNKS chunk maps sequentially per unit -> EXACT s0 at
// every chunk boundary. 512 threads, coalesced double2 loads.
// ---------------------------------------------------------------------------
__global__ __launch_bounds__(64)
void lindley_scan_kernel(const double2* __restrict__ dm,
                         float* __restrict__ s0b) {
    const int h = blockIdx.x * 64 + threadIdx.x;   // grid = 8 blocks
    double xv = 0.0;
    s0b[h] = 0.0f;                                  // boundary 0: s0 = 0
    for (int c = 0; c + 1 < CHUNKS; ++c) {
        const double2 a = dm[c * HID + h];
        xv = fmax(xv + a.x, a.y);
        s0b[(c + 1) * HID + h] = (float)xv;
    }
}

// ---------------------------------------------------------------------------
// One recurrence step (~18 VALU).
// ---------------------------------------------------------------------------
#define STEP(P, TT, PE, QV)                                                   \
    {                                                                         \
        const float dfdt = fmaf(DF, (TT), ndftmx);                            \
        const float melt = __builtin_amdgcn_fmed3f(dfdt, s0, 0.0f);           \
        const float ps   = ((TT) <= TMN) ? (P) : 0.0f;                        \
        const float w    = melt - ps;                                         \
        s0 = s0 - w;                                                          \
        const float qs   = fmaxf(s1 - SM, 0.0f);                              \
        const float m    = fminf(s1, SM);                                     \
        const float u    = fmaf(g, s1, qc);                                   \
        const float qb   = fminf(QM, __builtin_amdgcn_exp2f(u));              \
        const float npei = (PE)*ninv_sm;                                      \
        const float A    = (s1 + ((P) + w)) - qs;                             \
        const float B    = fmaf(m, npei, A);                                  \
        s1 = fmaxf(B - qb, 0.0f);                                             \
        QV = qb + qs;                                                         \
    }

// ---------------------------------------------------------------------------
// Main chunked scan. Chunk c starts at boundary c-3 with EXACT s0 and s1=0;
// 384 warmup steps contract s1 error (climb <= ~310 steps worst case, then
// exact qs-collapse / exponential contraction). Chunks 0-2 start at t=0.
// ~3 waves/SIMD: independent chunk chains overlap on the issue port
// (chain ~155 cy/step vs issue ~42 cy/step -> k~3 multiplies throughput).
// ---------------------------------------------------------------------------
__global__ __launch_bounds__(64, 1)
void hydro_chunk_kernel(const float4* __restrict__ ptp,
                        const float*  __restrict__ s0b,
                        const float*  __restrict__ f_,
                        const float*  __restrict__ smax_,
                        const float*  __restrict__ qmax_,
                        const float*  __restrict__ df_,
                        const float*  __restrict__ tmax_,
                        const float*  __restrict__ tmin_,
                        float*        __restrict__ q) {
    const int b     = blockIdx.x;          // 0..CHUNKS*8-1
    const int chunk = b >> 3;
    const int h     = ((b & 7) << 6) | (int)threadIdx.x;

    const float F   = f_[h];
    const float SM  = smax_[h];
    const float QM  = qmax_[h];
    const float DF  = df_[h];
    const float TMX = tmax_[h];
    const float TMN = tmin_[h];

    const float g       = F * 1.4426950408889634f;   // f * log2(e)
    const float qc      = __log2f(QM) - g * SM;       // log2(qmax) - g*smax
    const float ninv_sm = -1.0f / SM;
    const float ndftmx  = -(DF * TMX);

    const int cL    = chunk * LBASE;
    const int cE    = (cL + LBASE < T_STEPS) ? (cL + LBASE) : T_STEPS;
    const int start = (chunk >= WARMCH) ? (cL - WARMCH * LBASE) : 0;

    float s0 = (chunk >= WARMCH) ? s0b[(chunk - WARMCH) * HID + h] : 0.0f;
    float s1 = 0.0f;

    const float4* vp = ptp + start;
    asm volatile("" : "+v"(vp));           // keep loads vector (in-order vmcnt)

    float4 bufA[8], bufB[8];
#pragma unroll
    for (int i = 0; i < 8; ++i) bufA[i] = vp[i];
#pragma unroll
    for (int i = 0; i < 8; ++i) bufB[i] = vp[8 + i];

    float qv[8];

    const int nWarm16 = (cL - start) >> 4;            // 0,8,16 or 24
    for (int it = 0; it < nWarm16; ++it) {
#pragma unroll
        for (int i = 0; i < 8; ++i) STEP(bufA[i].x, bufA[i].y, bufA[i].z, qv[i]);
#pragma unroll
        for (int i = 0; i < 8; ++i) bufA[i] = vp[16 + i];
#pragma unroll
        for (int i = 0; i < 8; ++i) STEP(bufB[i].x, bufB[i].y, bufB[i].z, qv[i]);
#pragma unroll
        for (int i = 0; i < 8; ++i) bufB[i] = vp[24 + i];
        vp += 16;
    }

    char* qbase  = (char*)q;
    unsigned off = (unsigned)cL * (HID * 4u) + (unsigned)h * 4u;

    const int nOut16 = (cE - cL) >> 4;                // 8, or 5 for tail chunk
    for (int it = 0; it < nOut16; ++it) {
#pragma unroll
        for (int i = 0; i < 8; ++i) STEP(bufA[i].x, bufA[i].y, bufA[i].z, qv[i]);
#pragma unroll
        for (int i = 0; i < 8; ++i) bufA[i] = vp[16 + i];
#pragma unroll
        for (int i = 0; i < 8; ++i)
            *(float*)(qbase + off + (unsigned)i * 2048u) = qv[i];
        off += 8u * 2048u;
#pragma unroll
        for (int i = 0; i < 8; ++i) STEP(bufB[i].x, bufB[i].y, bufB[i].z, qv[i]);
#pragma unroll
        for (int i = 0; i < 8; ++i) bufB[i] = vp[24 + i];
#pragma unroll
        for (int i = 0; i < 8; ++i)
            *(float*)(qbase + off + (unsigned)i * 2048u) = qv[i];
        off += 8u * 2048u;
        vp += 16;
    }
}

// ---------------------------------------------------------------------------
// Fallback: full-serial scan (correct for any ws_size), pet inline.
// ---------------------------------------------------------------------------
__global__ __launch_bounds__(64)
void hydro_serial_kernel(const float* __restrict__ x,
                         const float* __restrict__ f_,
                         const float* __restrict__ smax_,
                         const float* __restrict__ qmax_,
                         const float* __restrict__ df_,
                         const float* __restrict__ tmax_,
                         const float* __restrict__ tmin_,
                         float* __restrict__ q) {
    const int h = blockIdx.x * 64 + threadIdx.x;
    const float F = f_[h], SM = smax_[h], QM = qmax_[h];
    const float DF = df_[h], TMX = tmax_[h], TMN = tmin_[h];
    const float g       = F * 1.4426950408889634f;
    const float qc      = __log2f(QM) - g * SM;
    const float ninv_sm = -1.0f / SM;
    const float ndftmx  = -(DF * TMX);
    float s0 = 0.f, s1 = 0.f;
    char* qbase  = (char*)q;
    unsigned off = (unsigned)h * 4u;
    for (int t = 0; t < T_STEPS; ++t) {
        const float p  = x[3 * t + 0];
        const float tt = x[3 * t + 1];
        const float ld = x[3 * t + 2];
        const float esat = 0.611f * __expf(17.3f * tt / (tt + 237.3f));
        const float pe   = 29.8f * (ld * 24.0f) * esat / (tt + 273.2f);
        float qv;
        STEP(p, tt, pe, qv);
        *(float*)(qbase + off) = qv;
        off += 2048u;
    }
}

// ---------------------------------------------------------------------------
extern "C" void kernel_launch(void* const* d_in, const int* in_sizes, int n_in,
                              void* d_out, int out_size, void* d_ws,
                              size_t ws_size, hipStream_t stream) {
    const float* x    = (const float*)d_in[0];
    const float* f    = (const float*)d_in[1];
    const float* smax = (const float*)d_in[2];
    const float* qmax = (const float*)d_in[3];
    const float* df   = (const float*)d_in[4];
    const float* tmax = (const float*)d_in[5];
    const float* tmin = (const float*)d_in[6];
    float* q = (float*)d_out;

    const size_t PTP_BYTES = (size_t)NPAD * sizeof(float4);          // ~801 KB
    const size_t DM_OFF    = PTP_BYTES;
    const size_t DM_BYTES  = (size_t)CHUNKS * HID * sizeof(double2); // ~3.2 MB
    const size_t S0B_OFF   = DM_OFF + DM_BYTES;
    const size_t S0B_BYTES = (size_t)CHUNKS * HID * sizeof(float);   // ~800 KB
    const size_t NEED      = S0B_OFF + S0B_BYTES;

    if (ws_size >= NEED) {
        float4*  ptp = (float4*)d_ws;
        double2* dm  = (double2*)((char*)d_ws + DM_OFF);
        float*   s0b = (float*)((char*)d_ws + S0B_OFF);

        pet_pack_kernel<<<(NPAD + 255) / 256, 256, 0, stream>>>(x, ptp);
        lindley_agg_kernel<<<CHUNKS * 8, 64, 0, stream>>>(ptp, df, tmax, tmin, dm);
        lindley_scan_kernel<<<HID / 64, 64, 0, stream>>>(dm, s0b);
        hydro_chunk_kernel<<<CHUNKS * 8, 64, 0, stream>>>(
            ptp, s0b, f, smax, qmax, df, tmax, tmin, q);
    } else {
        hydro_serial_kernel<<<HID / 64, 64, 0, stream>>>(
            x, f, smax, qmax, df, tmax, tmin, q);
    }
}

// Round 8
// 125.571 us; speedup vs baseline: 1.0312x; 1.0312x over previous
//
#include <hip/hip_runtime.h>

#define T_STEPS 50000
#define HID     512
#define LBASE   176
#define CHUNKS  ((T_STEPS + LBASE - 1) / LBASE)   // 285 (tail chunk = 16 steps)
#define WARMCH  2                                  // s1 warmup = 352 steps
#define NPAD    (T_STEPS + 64)                     // prefetch overshoot pad

// ---------------------------------------------------------------------------
// Kernel 1: pack per-step uniform scalars {prcp, temp, pet} as float4.
// ---------------------------------------------------------------------------
__global__ void pet_pack_kernel(const float* __restrict__ x,
                                float4* __restrict__ ptp) {
    int i = blockIdx.x * 256 + threadIdx.x;
    if (i >= NPAD) return;
    float4 v = make_float4(0.f, 0.f, 0.f, 0.f);
    if (i < T_STEPS) {
        float p  = x[3 * i + 0];
        float tt = x[3 * i + 1];
        float ld = x[3 * i + 2];
        float esat = 0.611f * __expf(17.3f * tt / (tt + 237.3f));
        float pe   = 29.8f * (ld * 24.0f) * esat / (tt + 273.2f);
        v = make_float4(p, tt, pe, 0.f);
    }
    ptp[i] = v;
}

// ---------------------------------------------------------------------------
// Snow bucket is max-plus linear (Lindley):  s0' = max(s0 + d, ps),
// d = ps - cap, cap = max(df*(t-tmax), 0).  Segment summary (D, M) composes
// as x -> max(x + D, M).   Pass A: per-(chunk,unit) aggregates in double.
// 256-thread blocks: 2 blocks per chunk (units 0-255 / 256-511).
// ---------------------------------------------------------------------------
__global__ __launch_bounds__(256)
void lindley_agg_kernel(const float4* __restrict__ ptp,
                        const float* __restrict__ df_,
                        const float* __restrict__ tmax_,
                        const float* __restrict__ tmin_,
                        double2* __restrict__ dm) {
    const int b     = blockIdx.x;          // 0..CHUNKS*2-1
    const int chunk = b >> 1;
    const int h     = ((b & 1) << 8) | (int)threadIdx.x;

    const float DF = df_[h], TMX = tmax_[h], TMN = tmin_[h];
    const float ndftmx = -(DF * TMX);

    const int cL  = chunk * LBASE;
    const int cE  = (cL + LBASE < T_STEPS) ? (cL + LBASE) : T_STEPS;
    const int n16 = (cE - cL) >> 4;        // 11, or 1 for the tail chunk

    const float4* vp = ptp + cL;
    asm volatile("" : "+v"(vp));           // keep loads vector (in-order vmcnt)

    float4 bufA[8], bufB[8];
#pragma unroll
    for (int i = 0; i < 8; ++i) bufA[i] = vp[i];
#pragma unroll
    for (int i = 0; i < 8; ++i) bufB[i] = vp[8 + i];

    double D = 0.0, M = -1.0e300;
#define AGG(P, TT)                                                            \
    {                                                                         \
        const float cap = fmaxf(fmaf(DF, (TT), ndftmx), 0.0f);                \
        const float ps  = ((TT) <= TMN) ? (P) : 0.0f;                         \
        const double d  = (double)ps - (double)cap;                           \
        D += d;                                                               \
        M = fmax(M + d, (double)ps);                                          \
    }
    for (int it = 0; it < n16; ++it) {
#pragma unroll
        for (int i = 0; i < 8; ++i) AGG(bufA[i].x, bufA[i].y);
#pragma unroll
        for (int i = 0; i < 8; ++i) bufA[i] = vp[16 + i];
#pragma unroll
        for (int i = 0; i < 8; ++i) AGG(bufB[i].x, bufB[i].y);
#pragma unroll
        for (int i = 0; i < 8; ++i) bufB[i] = vp[24 + i];
        vp += 16;
    }
#undef AGG
    dm[chunk * HID + h] = make_double2(D, M);
}

// ---------------------------------------------------------------------------
// Pass B: compose the CHUNKS chunk maps sequentially per unit -> EXACT s0 at
// every chunk boundary. 512 threads, coalesced double2 loads.
// ---------------------------------------------------------------------------
__global__ __launch_bounds__(64)
void lindley_scan_kernel(const double2* __restrict__ dm,
                         float* __restrict__ s0b) {
    const int h = blockIdx.x * 64 + threadIdx.x;   // grid = 8 blocks
    double xv = 0.0;
    s0b[h] = 0.0f;                                  // boundary 0: s0 = 0
    for (int c = 0; c + 1 < CHUNKS; ++c) {
        const double2 a = dm[c * HID + h];
        xv = fmax(xv + a.x, a.y);
        s0b[(c + 1) * HID + h] = (float)xv;
    }
}

// ---------------------------------------------------------------------------
// One recurrence step (~18 VALU).
// ---------------------------------------------------------------------------
#define STEP(P, TT, PE, QV)                                                   \
    {                                                                         \
        const float dfdt = fmaf(DF, (TT), ndftmx);                            \
        const float melt = __builtin_amdgcn_fmed3f(dfdt, s0, 0.0f);           \
        const float ps   = ((TT) <= TMN) ? (P) : 0.0f;                        \
        const float w    = melt - ps;                                         \
        s0 = s0 - w;                                                          \
        const float qs   = fmaxf(s1 - SM, 0.0f);                              \
        const float m    = fminf(s1, SM);                                     \
        const float u    = fmaf(g, s1, qc);                                   \
        const float qb   = fminf(QM, __builtin_amdgcn_exp2f(u));              \
        const float npei = (PE)*ninv_sm;                                      \
        const float A    = (s1 + ((P) + w)) - qs;                             \
        const float B    = fmaf(m, npei, A);                                  \
        s1 = fmaxf(B - qb, 0.0f);                                             \
        QV = qb + qs;                                                         \
    }

// ---------------------------------------------------------------------------
// Main chunked scan. 256-thread blocks (4 waves), 2 blocks per chunk ->
// 570 workgroups, 2280 waves, ~2.2 waves/SIMD all co-resident (round-7
// showed 64-thread wgs cap at ~1600 resident waves; 4x fewer wgs avoids it).
// Chunk c starts at boundary c-2 with EXACT s0 (pass B) and s1=0; 352 warmup
// steps: ~170-step climb to the s1 equilibrium band + >=180 steps at
// lambda = f*qb + pe/smax >= 0.083 -> e^-15, plus exact one-step collapse
// whenever s1 crosses smax. Chunks 0-1 start at t=0 (fully exact).
// ---------------------------------------------------------------------------
__global__ __launch_bounds__(256)
void hydro_chunk_kernel(const float4* __restrict__ ptp,
                        const float*  __restrict__ s0b,
                        const float*  __restrict__ f_,
                        const float*  __restrict__ smax_,
                        const float*  __restrict__ qmax_,
                        const float*  __restrict__ df_,
                        const float*  __restrict__ tmax_,
                        const float*  __restrict__ tmin_,
                        float*        __restrict__ q) {
    const int b     = blockIdx.x;          // 0..CHUNKS*2-1
    const int chunk = b >> 1;
    const int h     = ((b & 1) << 8) | (int)threadIdx.x;

    const float F   = f_[h];
    const float SM  = smax_[h];
    const float QM  = qmax_[h];
    const float DF  = df_[h];
    const float TMX = tmax_[h];
    const float TMN = tmin_[h];

    const float g       = F * 1.4426950408889634f;   // f * log2(e)
    const float qc      = __log2f(QM) - g * SM;       // log2(qmax) - g*smax
    const float ninv_sm = -1.0f / SM;
    const float ndftmx  = -(DF * TMX);

    const int cL    = chunk * LBASE;
    const int cE    = (cL + LBASE < T_STEPS) ? (cL + LBASE) : T_STEPS;
    const int start = (chunk >= WARMCH) ? (cL - WARMCH * LBASE) : 0;

    float s0 = (chunk >= WARMCH) ? s0b[(chunk - WARMCH) * HID + h] : 0.0f;
    float s1 = 0.0f;

    const float4* vp = ptp + start;
    asm volatile("" : "+v"(vp));           // keep loads vector (in-order vmcnt)

    float4 bufA[8], bufB[8];
#pragma unroll
    for (int i = 0; i < 8; ++i) bufA[i] = vp[i];
#pragma unroll
    for (int i = 0; i < 8; ++i) bufB[i] = vp[8 + i];

    float qvA[8], qvB[8];                  // separate sets: wider store-WAR gap

    const int nWarm16 = (cL - start) >> 4;            // 0, 11, or 22
    for (int it = 0; it < nWarm16; ++it) {
#pragma unroll
        for (int i = 0; i < 8; ++i) STEP(bufA[i].x, bufA[i].y, bufA[i].z, qvA[i]);
#pragma unroll
        for (int i = 0; i < 8; ++i) bufA[i] = vp[16 + i];
#pragma unroll
        for (int i = 0; i < 8; ++i) STEP(bufB[i].x, bufB[i].y, bufB[i].z, qvB[i]);
#pragma unroll
        for (int i = 0; i < 8; ++i) bufB[i] = vp[24 + i];
        vp += 16;
    }

    char* qbase  = (char*)q;
    unsigned off = (unsigned)cL * (HID * 4u) + (unsigned)h * 4u;

    const int nOut16 = (cE - cL) >> 4;                // 11, or 1 for tail
    for (int it = 0; it < nOut16; ++it) {
#pragma unroll
        for (int i = 0; i < 8; ++i) STEP(bufA[i].x, bufA[i].y, bufA[i].z, qvA[i]);
#pragma unroll
        for (int i = 0; i < 8; ++i) bufA[i] = vp[16 + i];
#pragma unroll
        for (int i = 0; i < 8; ++i)
            *(float*)(qbase + off + (unsigned)i * 2048u) = qvA[i];
        off += 8u * 2048u;
#pragma unroll
        for (int i = 0; i < 8; ++i) STEP(bufB[i].x, bufB[i].y, bufB[i].z, qvB[i]);
#pragma unroll
        for (int i = 0; i < 8; ++i) bufB[i] = vp[24 + i];
#pragma unroll
        for (int i = 0; i < 8; ++i)
            *(float*)(qbase + off + (unsigned)i * 2048u) = qvB[i];
        off += 8u * 2048u;
        vp += 16;
    }
}

// ---------------------------------------------------------------------------
// Fallback: full-serial scan (correct for any ws_size), pet inline.
// ---------------------------------------------------------------------------
__global__ __launch_bounds__(64)
void hydro_serial_kernel(const float* __restrict__ x,
                         const float* __restrict__ f_,
                         const float* __restrict__ smax_,
                         const float* __restrict__ qmax_,
                         const float* __restrict__ df_,
                         const float* __restrict__ tmax_,
                         const float* __restrict__ tmin_,
                         float* __restrict__ q) {
    const int h = blockIdx.x * 64 + threadIdx.x;
    const float F = f_[h], SM = smax_[h], QM = qmax_[h];
    const float DF = df_[h], TMX = tmax_[h], TMN = tmin_[h];
    const float g       = F * 1.4426950408889634f;
    const float qc      = __log2f(QM) - g * SM;
    const float ninv_sm = -1.0f / SM;
    const float ndftmx  = -(DF * TMX);
    float s0 = 0.f, s1 = 0.f;
    char* qbase  = (char*)q;
    unsigned off = (unsigned)h * 4u;
    for (int t = 0; t < T_STEPS; ++t) {
        const float p  = x[3 * t + 0];
        const float tt = x[3 * t + 1];
        const float ld = x[3 * t + 2];
        const float esat = 0.611f * __expf(17.3f * tt / (tt + 237.3f));
        const float pe   = 29.8f * (ld * 24.0f) * esat / (tt + 273.2f);
        float qv;
        STEP(p, tt, pe, qv);
        *(float*)(qbase + off) = qv;
        off += 2048u;
    }
}

// ---------------------------------------------------------------------------
extern "C" void kernel_launch(void* const* d_in, const int* in_sizes, int n_in,
                              void* d_out, int out_size, void* d_ws,
                              size_t ws_size, hipStream_t stream) {
    const float* x    = (const float*)d_in[0];
    const float* f    = (const float*)d_in[1];
    const float* smax = (const float*)d_in[2];
    const float* qmax = (const float*)d_in[3];
    const float* df   = (const float*)d_in[4];
    const float* tmax = (const float*)d_in[5];
    const float* tmin = (const float*)d_in[6];
    float* q = (float*)d_out;

    const size_t PTP_BYTES = (size_t)NPAD * sizeof(float4);          // ~801 KB
    const size_t DM_OFF    = PTP_BYTES;
    const size_t DM_BYTES  = (size_t)CHUNKS * HID * sizeof(double2); // ~2.3 MB
    const size_t S0B_OFF   = DM_OFF + DM_BYTES;
    const size_t S0B_BYTES = (size_t)CHUNKS * HID * sizeof(float);   // ~0.6 MB
    const size_t NEED      = S0B_OFF + S0B_BYTES;

    if (ws_size >= NEED) {
        float4*  ptp = (float4*)d_ws;
        double2* dm  = (double2*)((char*)d_ws + DM_OFF);
        float*   s0b = (float*)((char*)d_ws + S0B_OFF);

        pet_pack_kernel<<<(NPAD + 255) / 256, 256, 0, stream>>>(x, ptp);
        lindley_agg_kernel<<<CHUNKS * 2, 256, 0, stream>>>(ptp, df, tmax, tmin, dm);
        lindley_scan_kernel<<<HID / 64, 64, 0, stream>>>(dm, s0b);
        hydro_chunk_kernel<<<CHUNKS * 2, 256, 0, stream>>>(
            ptp, s0b, f, smax, qmax, df, tmax, tmin, q);
    } else {
        hydro_serial_kernel<<<HID / 64, 64, 0, stream>>>(
            x, f, smax, qmax, df, tmax, tmin, q);
    }
}

// Round 9
// 113.256 us; speedup vs baseline: 1.1433x; 1.1087x over previous
//
#include <hip/hip_runtime.h>

#define T_STEPS 50000
#define HID     512
#define LBASE   512
#define CHUNKS  ((T_STEPS + LBASE - 1) / LBASE)   // 98 (tail chunk = 336 steps)
#define WARMCH  1                                  // s1 warmup = 512 steps
#define NPAD    (T_STEPS + 64)                     // prefetch overshoot pad

static_assert(CHUNKS == 98, "scan kernel prologue assumes 98 chunks");
static_assert((CHUNKS - 2) % 4 == 0, "scan unroll-4 layout");

// Force the 8 buffered {p,t,pe} values into live VGPRs at this point.
// The asm reads+writes each component, so all 8 loads must COMPLETE here
// (one s_waitcnt per 16 steps) and the values stay in registers — the
// compiler can no longer sink the loads to their uses (which made every
// step pay a ~190cy L2-hit latency in rounds 1-8: VGPR_Count stayed 52).
#define PIN8(B) asm volatile("" :                                  \
    "+v"(B[0].x), "+v"(B[0].y), "+v"(B[0].z),                      \
    "+v"(B[1].x), "+v"(B[1].y), "+v"(B[1].z),                      \
    "+v"(B[2].x), "+v"(B[2].y), "+v"(B[2].z),                      \
    "+v"(B[3].x), "+v"(B[3].y), "+v"(B[3].z),                      \
    "+v"(B[4].x), "+v"(B[4].y), "+v"(B[4].z),                      \
    "+v"(B[5].x), "+v"(B[5].y), "+v"(B[5].z),                      \
    "+v"(B[6].x), "+v"(B[6].y), "+v"(B[6].z),                      \
    "+v"(B[7].x), "+v"(B[7].y), "+v"(B[7].z))

#define PIN2D(a) asm volatile("" : "+v"(a.x), "+v"(a.y))

// ---------------------------------------------------------------------------
// Kernel 1: pack per-step uniform scalars {prcp, temp, pet} as float4.
// ---------------------------------------------------------------------------
__global__ void pet_pack_kernel(const float* __restrict__ x,
                                float4* __restrict__ ptp) {
    int i = blockIdx.x * 256 + threadIdx.x;
    if (i >= NPAD) return;
    float4 v = make_float4(0.f, 0.f, 0.f, 0.f);
    if (i < T_STEPS) {
        float p  = x[3 * i + 0];
        float tt = x[3 * i + 1];
        float ld = x[3 * i + 2];
        float esat = 0.611f * __expf(17.3f * tt / (tt + 237.3f));
        float pe   = 29.8f * (ld * 24.0f) * esat / (tt + 273.2f);
        v = make_float4(p, tt, pe, 0.f);
    }
    ptp[i] = v;
}

// ---------------------------------------------------------------------------
// Snow bucket is max-plus linear (Lindley): s0' = max(s0 + d, ps).
// Pass A: per-(chunk,unit) segment aggregates (D, M) in double.
// ---------------------------------------------------------------------------
__global__ __launch_bounds__(256)
void lindley_agg_kernel(const float4* __restrict__ ptp,
                        const float* __restrict__ df_,
                        const float* __restrict__ tmax_,
                        const float* __restrict__ tmin_,
                        double2* __restrict__ dm) {
    const int b     = blockIdx.x;          // 0..CHUNKS*2-1
    const int chunk = b >> 1;
    const int h     = ((b & 1) << 8) | (int)threadIdx.x;

    const float DF = df_[h], TMX = tmax_[h], TMN = tmin_[h];
    const float ndftmx = -(DF * TMX);

    const int cL  = chunk * LBASE;
    const int cE  = (cL + LBASE < T_STEPS) ? (cL + LBASE) : T_STEPS;
    const int n16 = (cE - cL) >> 4;        // 32, or 21 for the tail chunk

    const float4* vp = ptp + cL;
    asm volatile("" : "+v"(vp));           // keep loads vector (in-order vmcnt)

    float4 bufA[8], bufB[8];
#pragma unroll
    for (int i = 0; i < 8; ++i) bufA[i] = vp[i];
#pragma unroll
    for (int i = 0; i < 8; ++i) bufB[i] = vp[8 + i];

    double D = 0.0, M = -1.0e300;
#define AGG(P, TT)                                                            \
    {                                                                         \
        const float cap = fmaxf(fmaf(DF, (TT), ndftmx), 0.0f);                \
        const float ps  = ((TT) <= TMN) ? (P) : 0.0f;                         \
        const double d  = (double)ps - (double)cap;                           \
        D += d;                                                               \
        M = fmax(M + d, (double)ps);                                          \
    }
    for (int it = 0; it < n16; ++it) {
        PIN8(bufA);
#pragma unroll
        for (int i = 0; i < 8; ++i) AGG(bufA[i].x, bufA[i].y);
#pragma unroll
        for (int i = 0; i < 8; ++i) bufA[i] = vp[16 + i];
        PIN8(bufB);
#pragma unroll
        for (int i = 0; i < 8; ++i) AGG(bufB[i].x, bufB[i].y);
#pragma unroll
        for (int i = 0; i < 8; ++i) bufB[i] = vp[24 + i];
        vp += 16;
    }
#undef AGG
    dm[chunk * HID + h] = make_double2(D, M);
}

// ---------------------------------------------------------------------------
// Pass B: compose the 98 chunk maps sequentially per unit -> EXACT s0 at
// every chunk boundary. Depth-4 rotating prefetch with pins (was the hidden
// 24us: 97 serial L2-latency loads). 97 composes = 1 prologue + 24*4.
// Over-reads dm up to index 100 -> lands in the adjacent s0b region of the
// same workspace allocation (values unused; no fault).
// ---------------------------------------------------------------------------
__global__ __launch_bounds__(64)
void lindley_scan_kernel(const double2* __restrict__ dm,
                         float* __restrict__ s0b) {
    const int h = blockIdx.x * 64 + threadIdx.x;   // grid = 8 blocks
    const double2* dp = dm + h;
    double xv = 0.0;
    s0b[h] = 0.0f;                                  // boundary 0: s0 = 0

#define COMP(a, c)                                                            \
    {                                                                         \
        PIN2D(a);                                                             \
        xv = fmax(xv + a.x, a.y);                                             \
        s0b[(size_t)((c) + 1) * HID + h] = (float)xv;                         \
    }

    double2 p0 = dp[0];
    double2 p1 = dp[(size_t)1 * HID];
    double2 p2 = dp[(size_t)2 * HID];
    double2 p3 = dp[(size_t)3 * HID];

    COMP(p0, 0);
    p0 = dp[(size_t)4 * HID];

    for (int j = 0; j < 24; ++j) {
        const int c = 1 + 4 * j;
        COMP(p1, c);     p1 = dp[(size_t)(c + 4) * HID];
        COMP(p2, c + 1); p2 = dp[(size_t)(c + 5) * HID];
        COMP(p3, c + 2); p3 = dp[(size_t)(c + 6) * HID];
        COMP(p0, c + 3); p0 = dp[(size_t)(c + 7) * HID];
    }
#undef COMP
}

// ---------------------------------------------------------------------------
// One recurrence step (~18 VALU).
// ---------------------------------------------------------------------------
#define STEP(P, TT, PE, QV)                                                   \
    {                                                                         \
        const float dfdt = fmaf(DF, (TT), ndftmx);                            \
        const float melt = __builtin_amdgcn_fmed3f(dfdt, s0, 0.0f);           \
        const float ps   = ((TT) <= TMN) ? (P) : 0.0f;                        \
        const float w    = melt - ps;                                         \
        s0 = s0 - w;                                                          \
        const float qs   = fmaxf(s1 - SM, 0.0f);                              \
        const float m    = fminf(s1, SM);                                     \
        const float u    = fmaf(g, s1, qc);                                   \
        const float qb   = fminf(QM, __builtin_amdgcn_exp2f(u));              \
        const float npei = (PE)*ninv_sm;                                      \
        const float A    = (s1 + ((P) + w)) - qs;                             \
        const float B    = fmaf(m, npei, A);                                  \
        s1 = fmaxf(B - qb, 0.0f);                                             \
        QV = qb + qs;                                                         \
    }

// ---------------------------------------------------------------------------
// Main chunked scan. Chunk c starts at boundary c-1 with EXACT s0 (pass B)
// and s1=0; 512 warmup steps (validated at 400 in earlier rounds: absmax
// identical to fully-serial). Chunk 0 starts at t=0 (fully exact).
// 196 wgs x 256 thr = 784 waves, ~0.77/SIMD: with loads truly pinned in
// registers the wall is steps * max(chain, k*issue) -- latency eliminated.
// ---------------------------------------------------------------------------
__global__ __launch_bounds__(256)
void hydro_chunk_kernel(const float4* __restrict__ ptp,
                        const float*  __restrict__ s0b,
                        const float*  __restrict__ f_,
                        const float*  __restrict__ smax_,
                        const float*  __restrict__ qmax_,
                        const float*  __restrict__ df_,
                        const float*  __restrict__ tmax_,
                        const float*  __restrict__ tmin_,
                        float*        __restrict__ q) {
    const int b     = blockIdx.x;          // 0..CHUNKS*2-1
    const int chunk = b >> 1;
    const int h     = ((b & 1) << 8) | (int)threadIdx.x;

    const float F   = f_[h];
    const float SM  = smax_[h];
    const float QM  = qmax_[h];
    const float DF  = df_[h];
    const float TMX = tmax_[h];
    const float TMN = tmin_[h];

    const float g       = F * 1.4426950408889634f;   // f * log2(e)
    const float qc      = __log2f(QM) - g * SM;       // log2(qmax) - g*smax
    const float ninv_sm = -1.0f / SM;
    const float ndftmx  = -(DF * TMX);

    const int cL    = chunk * LBASE;
    const int cE    = (cL + LBASE < T_STEPS) ? (cL + LBASE) : T_STEPS;
    const int start = (chunk >= WARMCH) ? (cL - WARMCH * LBASE) : 0;

    float s0 = (chunk >= WARMCH) ? s0b[(chunk - WARMCH) * HID + h] : 0.0f;
    float s1 = 0.0f;

    const float4* vp = ptp + start;
    asm volatile("" : "+v"(vp));           // keep loads vector (in-order vmcnt)

    float4 bufA[8], bufB[8];
#pragma unroll
    for (int i = 0; i < 8; ++i) bufA[i] = vp[i];
#pragma unroll
    for (int i = 0; i < 8; ++i) bufB[i] = vp[8 + i];

    float qvA[8], qvB[8];

    const int nWarm16 = (cL - start) >> 4;            // 0 or 32
    for (int it = 0; it < nWarm16; ++it) {
        PIN8(bufA);
#pragma unroll
        for (int i = 0; i < 8; ++i) STEP(bufA[i].x, bufA[i].y, bufA[i].z, qvA[i]);
#pragma unroll
        for (int i = 0; i < 8; ++i) bufA[i] = vp[16 + i];
        PIN8(bufB);
#pragma unroll
        for (int i = 0; i < 8; ++i) STEP(bufB[i].x, bufB[i].y, bufB[i].z, qvB[i]);
#pragma unroll
        for (int i = 0; i < 8; ++i) bufB[i] = vp[24 + i];
        vp += 16;
    }

    char* qbase  = (char*)q;
    unsigned off = (unsigned)cL * (HID * 4u) + (unsigned)h * 4u;

    const int nOut16 = (cE - cL) >> 4;                // 32, or 21 for tail
    for (int it = 0; it < nOut16; ++it) {
        PIN8(bufA);
#pragma unroll
        for (int i = 0; i < 8; ++i) STEP(bufA[i].x, bufA[i].y, bufA[i].z, qvA[i]);
#pragma unroll
        for (int i = 0; i < 8; ++i) bufA[i] = vp[16 + i];
#pragma unroll
        for (int i = 0; i < 8; ++i)
            *(float*)(qbase + off + (unsigned)i * 2048u) = qvA[i];
        off += 8u * 2048u;
        PIN8(bufB);
#pragma unroll
        for (int i = 0; i < 8; ++i) STEP(bufB[i].x, bufB[i].y, bufB[i].z, qvB[i]);
#pragma unroll
        for (int i = 0; i < 8; ++i) bufB[i] = vp[24 + i];
#pragma unroll
        for (int i = 0; i < 8; ++i)
            *(float*)(qbase + off + (unsigned)i * 2048u) = qvB[i];
        off += 8u * 2048u;
        vp += 16;
    }
}

// ---------------------------------------------------------------------------
// Fallback: full-serial scan (correct for any ws_size), pet inline.
// ---------------------------------------------------------------------------
__global__ __launch_bounds__(64)
void hydro_serial_kernel(const float* __restrict__ x,
                         const float* __restrict__ f_,
                         const float* __restrict__ smax_,
                         const float* __restrict__ qmax_,
                         const float* __restrict__ df_,
                         const float* __restrict__ tmax_,
                         const float* __restrict__ tmin_,
                         float* __restrict__ q) {
    const int h = blockIdx.x * 64 + threadIdx.x;
    const float F = f_[h], SM = smax_[h], QM = qmax_[h];
    const float DF = df_[h], TMX = tmax_[h], TMN = tmin_[h];
    const float g       = F * 1.4426950408889634f;
    const float qc      = __log2f(QM) - g * SM;
    const float ninv_sm = -1.0f / SM;
    const float ndftmx  = -(DF * TMX);
    float s0 = 0.f, s1 = 0.f;
    char* qbase  = (char*)q;
    unsigned off = (unsigned)h * 4u;
    for (int t = 0; t < T_STEPS; ++t) {
        const float p  = x[3 * t + 0];
        const float tt = x[3 * t + 1];
        const float ld = x[3 * t + 2];
        const float esat = 0.611f * __expf(17.3f * tt / (tt + 237.3f));
        const float pe   = 29.8f * (ld * 24.0f) * esat / (tt + 273.2f);
        float qv;
        STEP(p, tt, pe, qv);
        *(float*)(qbase + off) = qv;
        off += 2048u;
    }
}

// ---------------------------------------------------------------------------
extern "C" void kernel_launch(void* const* d_in, const int* in_sizes, int n_in,
                              void* d_out, int out_size, void* d_ws,
                              size_t ws_size, hipStream_t stream) {
    const float* x    = (const float*)d_in[0];
    const float* f    = (const float*)d_in[1];
    const float* smax = (const float*)d_in[2];
    const float* qmax = (const float*)d_in[3];
    const float* df   = (const float*)d_in[4];
    const float* tmax = (const float*)d_in[5];
    const float* tmin = (const float*)d_in[6];
    float* q = (float*)d_out;

    const size_t PTP_BYTES = (size_t)NPAD * sizeof(float4);          // ~801 KB
    const size_t DM_OFF    = PTP_BYTES;
    const size_t DM_BYTES  = (size_t)CHUNKS * HID * sizeof(double2); // ~784 KB
    const size_t S0B_OFF   = DM_OFF + DM_BYTES;
    const size_t S0B_BYTES = (size_t)CHUNKS * HID * sizeof(float);   // ~196 KB
    const size_t NEED      = S0B_OFF + S0B_BYTES + 65536;            // scan over-read pad

    if (ws_size >= NEED) {
        float4*  ptp = (float4*)d_ws;
        double2* dm  = (double2*)((char*)d_ws + DM_OFF);
        float*   s0b = (float*)((char*)d_ws + S0B_OFF);

        pet_pack_kernel<<<(NPAD + 255) / 256, 256, 0, stream>>>(x, ptp);
        lindley_agg_kernel<<<CHUNKS * 2, 256, 0, stream>>>(ptp, df, tmax, tmin, dm);
        lindley_scan_kernel<<<HID / 64, 64, 0, stream>>>(dm, s0b);
        hydro_chunk_kernel<<<CHUNKS * 2, 256, 0, stream>>>(
            ptp, s0b, f, smax, qmax, df, tmax, tmin, q);
    } else {
        hydro_serial_kernel<<<HID / 64, 64, 0, stream>>>(
            x, f, smax, qmax, df, tmax, tmin, q);
    }
}

// Round 15
// 84.579 us; speedup vs baseline: 1.5309x; 1.3391x over previous
//
#include <hip/hip_runtime.h>

#define T_STEPS 50000
#define HID     512
#define LBASE   512
#define CHUNKS  98             // ceil(50000/512); tail chunk = 336 steps
#define NPAD    (T_STEPS + 64)
#define SDMAX   (2 * LBASE)    // warmup(512) + output(512) float4 = 16384 B LDS

static_assert((T_STEPS + LBASE - 1) / LBASE == CHUNKS, "chunk count");
static_assert(LBASE % 16 == 0, "16-step bodies");

#define PIN2D(a) asm volatile("" : "+v"(a.x), "+v"(a.y))

// ---------------------------------------------------------------------------
// Kernel 1: pack per-step uniform scalars {prcp, temp, pet} as float4.
// ---------------------------------------------------------------------------
__global__ void pet_pack_kernel(const float* __restrict__ x,
                                float4* __restrict__ ptp) {
    int i = blockIdx.x * 256 + threadIdx.x;
    if (i >= NPAD) return;
    float4 v = make_float4(0.f, 0.f, 0.f, 0.f);
    if (i < T_STEPS) {
        float p  = x[3 * i + 0];
        float tt = x[3 * i + 1];
        float ld = x[3 * i + 2];
        float esat = 0.611f * __expf(17.3f * tt / (tt + 237.3f));
        float pe   = 29.8f * (ld * 24.0f) * esat / (tt + 273.2f);
        v = make_float4(p, tt, pe, 0.f);
    }
    ptp[i] = v;
}

// ---------------------------------------------------------------------------
// Pass A: snow bucket is max-plus linear (Lindley): s0' = max(s0 + d, ps),
// d = ps - cap, cap = max(df*(t-tmax), 0). Segment (D, M), composes as
// x -> max(x + D, M). Per-step data is block-uniform -> stage the chunk's
// stream in LDS once, then the loop is broadcast ds_read_b128 (conflict-free;
// compiler pipelines DS reads with partial lgkmcnt waits — guide m97 asm).
// ---------------------------------------------------------------------------
__global__ __launch_bounds__(256)
void lindley_agg_kernel(const float4* __restrict__ ptp,
                        const float* __restrict__ df_,
                        const float* __restrict__ tmax_,
                        const float* __restrict__ tmin_,
                        double2* __restrict__ dm) {
    __shared__ float4 sd[LBASE];
    const int b     = blockIdx.x;          // 0..CHUNKS*2-1
    const int chunk = b >> 1;
    const int h     = ((b & 1) << 8) | (int)threadIdx.x;

    const float DF = df_[h], TMX = tmax_[h], TMN = tmin_[h];
    const float ndftmx = -(DF * TMX);

    const int cL = chunk * LBASE;
    const int cE = (cL + LBASE < T_STEPS) ? (cL + LBASE) : T_STEPS;
    const int n  = cE - cL;                // 512, or 336 for tail

    for (int i = threadIdx.x; i < n; i += 256) sd[i] = ptp[cL + i];
    __syncthreads();

    double D = 0.0, M = -1.0e300;
    const int n16 = n >> 4;
    for (int it = 0; it < n16; ++it) {
        const int base = it * 16;
#pragma unroll
        for (int i = 0; i < 16; ++i) {
            const float4 v = sd[base + i];
            const float cap = fmaxf(fmaf(DF, v.y, ndftmx), 0.0f);
            const float ps  = (v.y <= TMN) ? v.x : 0.0f;
            const double d  = (double)ps - (double)cap;
            D += d;
            M = fmax(M + d, (double)ps);
        }
    }
    dm[chunk * HID + h] = make_double2(D, M);
}

// ---------------------------------------------------------------------------
// Pass B: compose the 98 chunk maps sequentially per unit -> EXACT s0 at
// every boundary. Depth-4 rotating prefetch (round-9 version: passed).
// Over-reads dm up to index 100 -> lands in the adjacent s0b region of the
// same workspace allocation (values unused; no fault).
// ---------------------------------------------------------------------------
__global__ __launch_bounds__(64)
void lindley_scan_kernel(const double2* __restrict__ dm,
                         float* __restrict__ s0b) {
    const int h = blockIdx.x * 64 + threadIdx.x;   // grid = 8 blocks
    const double2* dp = dm + h;
    double xv = 0.0;
    s0b[h] = 0.0f;                                  // boundary 0: s0 = 0

#define COMP(a, c)                                                            \
    {                                                                         \
        PIN2D(a);                                                             \
        xv = fmax(xv + a.x, a.y);                                             \
        s0b[(size_t)((c) + 1) * HID + h] = (float)xv;                         \
    }

    double2 p0 = dp[0];
    double2 p1 = dp[(size_t)1 * HID];
    double2 p2 = dp[(size_t)2 * HID];
    double2 p3 = dp[(size_t)3 * HID];

    COMP(p0, 0);
    p0 = dp[(size_t)4 * HID];

    for (int j = 0; j < 24; ++j) {
        const int c = 1 + 4 * j;
        COMP(p1, c);     p1 = dp[(size_t)(c + 4) * HID];
        COMP(p2, c + 1); p2 = dp[(size_t)(c + 5) * HID];
        COMP(p3, c + 2); p3 = dp[(size_t)(c + 6) * HID];
        COMP(p0, c + 3); p0 = dp[(size_t)(c + 7) * HID];
    }
#undef COMP
}

// ---------------------------------------------------------------------------
// One recurrence step (~18 VALU), math unchanged (validated absmax 0.25).
// ---------------------------------------------------------------------------
#define STEP(P, TT, PE, QV)                                                   \
    {                                                                         \
        const float dfdt = fmaf(DF, (TT), ndftmx);                            \
        const float melt = __builtin_amdgcn_fmed3f(dfdt, s0, 0.0f);           \
        const float ps   = ((TT) <= TMN) ? (P) : 0.0f;                        \
        const float w    = melt - ps;                                         \
        s0 = s0 - w;                                                          \
        const float qs   = fmaxf(s1 - SM, 0.0f);                              \
        const float m    = fminf(s1, SM);                                     \
        const float u    = fmaf(g, s1, qc);                                   \
        const float qb   = fminf(QM, __builtin_amdgcn_exp2f(u));              \
        const float npei = (PE)*ninv_sm;                                      \
        const float A    = (s1 + ((P) + w)) - qs;                             \
        const float B    = fmaf(m, npei, A);                                  \
        s1 = fmaxf(B - qb, 0.0f);                                             \
        QV = qb + qs;                                                         \
    }

// ---------------------------------------------------------------------------
// Main chunked scan, LDS-staged. Block = one chunk x 256 units; per-step
// {p,t,pe} is block-uniform -> stage [start, cE) in LDS once (16 KB), serial
// loop on broadcast ds_read_b128. ALIGNMENT INVARIANT (round-14 bug): the
// warmup span must be exactly LBASE so that s0b[chunk-1] (exact s0 at
// t = cL-LBASE) is applied at start = cL-LBASE. 512-step warmup passed in
// round 9 with absmax == fully-serial. Chunk 0 starts at t=0 (fully exact).
// ---------------------------------------------------------------------------
__global__ __launch_bounds__(256)
void hydro_chunk_kernel(const float4* __restrict__ ptp,
                        const float*  __restrict__ s0b,
                        const float*  __restrict__ f_,
                        const float*  __restrict__ smax_,
                        const float*  __restrict__ qmax_,
                        const float*  __restrict__ df_,
                        const float*  __restrict__ tmax_,
                        const float*  __restrict__ tmin_,
                        float*        __restrict__ q) {
    __shared__ float4 sd[SDMAX];
    const int b     = blockIdx.x;          // 0..CHUNKS*2-1
    const int chunk = b >> 1;
    const int h     = ((b & 1) << 8) | (int)threadIdx.x;

    const float F   = f_[h];
    const float SM  = smax_[h];
    const float QM  = qmax_[h];
    const float DF  = df_[h];
    const float TMX = tmax_[h];
    const float TMN = tmin_[h];

    const float g       = F * 1.4426950408889634f;   // f * log2(e)
    const float qc      = __log2f(QM) - g * SM;       // log2(qmax) - g*smax
    const float ninv_sm = -1.0f / SM;
    const float ndftmx  = -(DF * TMX);

    const int cL    = chunk * LBASE;
    const int cE    = (cL + LBASE < T_STEPS) ? (cL + LBASE) : T_STEPS;
    const int start = (chunk >= 1) ? (cL - LBASE) : 0;   // boundary-aligned!
    const int n     = cE - start;          // 512 (chunk 0), 1024, or 848 tail

    for (int i = threadIdx.x; i < n; i += 256) sd[i] = ptp[start + i];
    __syncthreads();

    float s0 = (chunk >= 1) ? s0b[(chunk - 1) * HID + h] : 0.0f;
    float s1 = 0.0f;

    const int nWarm16 = (cL - start) >> 4;            // 0 or 32
    for (int it = 0; it < nWarm16; ++it) {
        const int base = it * 16;
        float qv;
#pragma unroll
        for (int i = 0; i < 16; ++i) {
            const float4 v = sd[base + i];
            STEP(v.x, v.y, v.z, qv);
        }
        (void)qv;
    }

    char* qbase  = (char*)q;
    unsigned off = (unsigned)cL * 2048u + (unsigned)h * 4u;
    const int wbase = cL - start;                     // 0 or 512

    const int nOut16 = (cE - cL) >> 4;                // 32, or 21 for tail
    for (int it = 0; it < nOut16; ++it) {
        const int base = wbase + it * 16;
#pragma unroll
        for (int i = 0; i < 16; ++i) {
            const float4 v = sd[base + i];
            float qv;
            STEP(v.x, v.y, v.z, qv);
            *(float*)(qbase + off + (unsigned)i * 2048u) = qv;
        }
        off += 32768u;
    }
}

// ---------------------------------------------------------------------------
// Fallback: full-serial scan (correct for any ws_size), pet inline.
// ---------------------------------------------------------------------------
__global__ __launch_bounds__(64)
void hydro_serial_kernel(const float* __restrict__ x,
                         const float* __restrict__ f_,
                         const float* __restrict__ smax_,
                         const float* __restrict__ qmax_,
                         const float* __restrict__ df_,
                         const float* __restrict__ tmax_,
                         const float* __restrict__ tmin_,
                         float* __restrict__ q) {
    const int h = blockIdx.x * 64 + threadIdx.x;
    const float F = f_[h], SM = smax_[h], QM = qmax_[h];
    const float DF = df_[h], TMX = tmax_[h], TMN = tmin_[h];
    const float g       = F * 1.4426950408889634f;
    const float qc      = __log2f(QM) - g * SM;
    const float ninv_sm = -1.0f / SM;
    const float ndftmx  = -(DF * TMX);
    float s0 = 0.f, s1 = 0.f;
    for (int t = 0; t < T_STEPS; ++t) {
        const float p  = x[3 * t + 0];
        const float tt = x[3 * t + 1];
        const float ld = x[3 * t + 2];
        const float esat = 0.611f * __expf(17.3f * tt / (tt + 237.3f));
        const float pe   = 29.8f * (ld * 24.0f) * esat / (tt + 273.2f);
        float qv;
        STEP(p, tt, pe, qv);
        q[(size_t)t * HID + h] = qv;
    }
}

// ---------------------------------------------------------------------------
extern "C" void kernel_launch(void* const* d_in, const int* in_sizes, int n_in,
                              void* d_out, int out_size, void* d_ws,
                              size_t ws_size, hipStream_t stream) {
    const float* x    = (const float*)d_in[0];
    const float* f    = (const float*)d_in[1];
    const float* smax = (const float*)d_in[2];
    const float* qmax = (const float*)d_in[3];
    const float* df   = (const float*)d_in[4];
    const float* tmax = (const float*)d_in[5];
    const float* tmin = (const float*)d_in[6];
    float* q = (float*)d_out;

    const size_t PTP_BYTES = (size_t)NPAD * sizeof(float4);          // ~801 KB
    const size_t DM_OFF    = PTP_BYTES;
    const size_t DM_BYTES  = (size_t)CHUNKS * HID * sizeof(double2); // ~784 KB
    const size_t S0B_OFF   = DM_OFF + DM_BYTES;
    const size_t S0B_BYTES = (size_t)CHUNKS * HID * sizeof(float);   // ~196 KB
    const size_t NEED      = S0B_OFF + S0B_BYTES + 65536;            // scan pad

    if (ws_size >= NEED) {
        float4*  ptp = (float4*)d_ws;
        double2* dm  = (double2*)((char*)d_ws + DM_OFF);
        float*   s0b = (float*)((char*)d_ws + S0B_OFF);

        pet_pack_kernel<<<(NPAD + 255) / 256, 256, 0, stream>>>(x, ptp);
        lindley_agg_kernel<<<CHUNKS * 2, 256, 0, stream>>>(ptp, df, tmax, tmin, dm);
        lindley_scan_kernel<<<HID / 64, 64, 0, stream>>>(dm, s0b);
        hydro_chunk_kernel<<<CHUNKS * 2, 256, 0, stream>>>(
            ptp, s0b, f, smax, qmax, df, tmax, tmin, q);
    } else {
        hydro_serial_kernel<<<HID / 64, 64, 0, stream>>>(
            x, f, smax, qmax, df, tmax, tmin, q);
    }
}